// Round 21
// baseline (41.409 us; speedup 1.0000x reference)
//
#include <hip/hip_runtime.h>
#include <math.h>

// Chamfer loss via MFMA (math verified r12-r20, absmax 0).
// Round-21, from the r19/r20 model: warm loop is LDS-read-pipe-bound at an
// effective clock ~750MHz (harness duty cycle keeps DVFS low); VALU fold
// floor is 8.2K cy/SIMD. r20's 4-strip overflowed the 128-reg budget
// (VGPR=72 => rm in AGPRs, occupancy 21%). Fix: 3 STRIPS (RPB=384): live
// set ~118 regs fits launch_bounds(256,4); LDS reads 12.3K -> 4.1K cy/CU,
// W -> VALU-floor ~11-12us. Grid 1408 (4 blocks/CU by 33KB LDS). Odd
// nt0=33 handled by the verified self-pair tail.

typedef __attribute__((ext_vector_type(8)))  short  short8;
typedef __attribute__((ext_vector_type(16))) float  f32x16;

#define YS      8     // j-range splits per (dir,b)
#define RPB     384   // rows per block = 4 waves * 96 (3 strips of 32)
#define LTILES  33    // y-tiles in LDS (33 KB; 4 blocks/CU in 160KB)

#define MFMA2(da, db, A, B0, B1) \
    asm("v_mfma_f32_32x32x16_bf16 %0, %2, %3, 0\n\t" \
        "v_mfma_f32_32x32x16_bf16 %1, %2, %4, 0\n\t" \
        "s_nop 7\n\t" \
        "s_nop 7" \
        : "=&v"(da), "=&v"(db) \
        : "v"(A), "v"(B0), "v"(B1))

static __device__ __forceinline__ float min3f(float a, float b, float c) {
    float d;
    asm("v_min3_f32 %0, %1, %2, %3" : "=v"(d) : "v"(a), "v"(b), "v"(c));
    return d;
}

// fold one strip: 2 MFMAs (tiles c0,c1) + 16 v_min3 into rm
#define STRIP(rm, A, c0, c1) do { \
    f32x16 da, db; \
    MFMA2(da, db, A, c0, c1); \
    _Pragma("unroll") \
    for (int r = 0; r < 16; ++r) rm[r] = min3f(da[r], db[r], rm[r]); \
} while (0)

static inline int roundup_h(int v, int a) { return (v + a - 1) / a * a; }

static __device__ __forceinline__ unsigned short f2bf(float f) {
    union { float f; unsigned int u; } v; v.f = f;
    unsigned int r = v.u + 0x7FFFu + ((v.u >> 16) & 1u);  // RNE
    return (unsigned short)(r >> 16);
}
static __device__ __forceinline__ float bf2f(unsigned short s) {
    union { unsigned int u; float f; } v; v.u = ((unsigned int)s) << 16;
    return v.f;
}
static __device__ __forceinline__ unsigned int pk2(unsigned short lo,
                                                   unsigned short hi) {
    return (unsigned int)lo | ((unsigned int)hi << 16);
}

// all-reduce min over each 32-lane group: 4 DPP levels (VALU) + 1 swizzle
static __device__ __forceinline__ float allmin32(float v) {
    union { float f; int i; } u, t;
    u.f = v;
    t.i = __builtin_amdgcn_update_dpp(u.i, u.i, 0xB1, 0xF, 0xF, false);  // xor1
    u.f = fminf(u.f, t.f);
    t.i = __builtin_amdgcn_update_dpp(u.i, u.i, 0x4E, 0xF, 0xF, false);  // xor2
    u.f = fminf(u.f, t.f);
    t.i = __builtin_amdgcn_update_dpp(u.i, u.i, 0x124, 0xF, 0xF, false); // ror4
    u.f = fminf(u.f, t.f);
    t.i = __builtin_amdgcn_update_dpp(u.i, u.i, 0x128, 0xF, 0xF, false); // ror8
    u.f = fminf(u.f, t.f);
    t.i = __builtin_amdgcn_ds_swizzle(u.i, 0x401F);                      // xor16
    u.f = fminf(u.f, t.f);
    return u.f;
}

// bf16-split pieces of one point (verified K-pattern, r5/r7/r12)
struct PiecesT {
    unsigned short th[3], tl[3], yh[3], yl[3], n2h, n2l;
};
static __device__ __forceinline__ PiecesT pieces(float x, float y, float z) {
    PiecesT p;
    const float xs[3] = {x, y, z};
    const float n2 = x*x + y*y + z*z;
    #pragma unroll
    for (int c = 0; c < 3; ++c) {
        const float t = -2.0f * xs[c];
        p.th[c] = f2bf(t);      p.tl[c] = f2bf(t - bf2f(p.th[c]));
        p.yh[c] = f2bf(xs[c]);  p.yl[c] = f2bf(xs[c] - bf2f(p.yh[c]));
    }
    p.n2h = f2bf(n2); p.n2l = f2bf(n2 - bf2f(p.n2h));
    return p;
}

// Fused pack+sweep. Block = (dir, b, js, row-block of 384). 4 waves; wave w
// owns 96 rows (3 MFMA strips; one ds_read_b128 feeds all 3). Y-chunk
// packed into LDS once; A-frags built in regs from raw floats.
__global__ __launch_bounds__(256, 4) void fused_sweep(
    const float* __restrict__ pred, const float* __restrict__ targ,
    int B, int N, int M, int NpadP, int NpadT, int NpadMax,
    float* __restrict__ rowpart)
{
    const int tid  = threadIdx.x;
    const int w    = tid >> 6;
    const int lane = tid & 63;
    const int lc   = lane & 31, h = lane >> 5;

    const int SP = NpadMax / RPB;
    int t = blockIdx.x;
    const int sp  = t % SP;  t /= SP;
    const int js  = t % YS;  t /= YS;
    const int b   = t % B;   t /= B;
    const int dir = t;

    const float* __restrict__ xsrc = (dir == 0) ? pred : targ;
    const float* __restrict__ ysrc = (dir == 0) ? targ : pred;
    const int Nx  = (dir == 0) ? N : M;
    const int My  = (dir == 0) ? M : N;
    const int NpadX = (dir == 0) ? NpadP : NpadT;
    const int NpadY = (dir == 0) ? NpadT : NpadP;
    if (sp * RPB >= NpadX) return;          // block-uniform

    const int TM  = NpadY / 32;             // NpadY mult of 384 -> TM=264
    const int nt0 = (TM + YS - 1) / YS;     // 33
    const int t0  = js * nt0;
    const int ntc = min(TM - t0, nt0);      // tiles this chunk (>=1)
    if (ntc <= 0) return;

    __shared__ unsigned short ypack[LTILES * 32 * 16];  // 33 KB

    // ---- A-frags (3 strips) in regs from raw floats ----
    const unsigned short ONE = 0x3F80;
    const int row0 = sp * RPB + w * 96;
    short8 a0, a1, a2;
    #pragma unroll
    for (int s = 0; s < 3; ++s) {
        const int row = min(row0 + s * 32 + lc, Nx - 1);
        const float* sx = xsrc + ((size_t)b * Nx + row) * 3;
        const PiecesT p = pieces(sx[0], sx[1], sx[2]);
        short8 v;
        if (h == 0) {
            v[0]=p.th[0]; v[1]=p.th[1]; v[2]=p.th[2]; v[3]=p.tl[0];
            v[4]=p.tl[1]; v[5]=p.tl[2]; v[6]=p.th[0]; v[7]=p.th[1];
        } else {
            v[0]=p.th[2]; v[1]=p.tl[0]; v[2]=p.tl[1]; v[3]=p.tl[2];
            v[4]=ONE;     v[5]=ONE;     v[6]=p.n2h;   v[7]=p.n2l;
        }
        if      (s == 0) a0 = v;
        else if (s == 1) a1 = v;
        else             a2 = v;
    }

    f32x16 rm0, rm1, rm2;
    #pragma unroll
    for (int r = 0; r < 16; ++r) {
        rm0[r] = __builtin_inff(); rm1[r] = __builtin_inff();
        rm2[r] = __builtin_inff();
    }

    {   // single fill (ntc <= LTILES): pack y-chunk into LDS
        for (int i = tid; i < ntc * 32; i += 256) {
            const int gi  = min(t0 * 32 + i, My - 1);
            const float* sy = ysrc + ((size_t)b * My + gi) * 3;
            const PiecesT p = pieces(sy[0], sy[1], sy[2]);
            uint4 blo, bhi;
            blo.x = pk2(p.yh[0], p.yh[1]); blo.y = pk2(p.yh[2], p.yh[0]);
            blo.z = pk2(p.yh[1], p.yh[2]); blo.w = pk2(p.yl[0], p.yl[1]);
            bhi.x = pk2(p.yl[2], p.yl[0]); bhi.y = pk2(p.yl[1], p.yl[2]);
            bhi.z = pk2(p.n2h,  p.n2l);    bhi.w = pk2(ONE,  ONE);
            const int tile = i >> 5, pos = i & 31;
            uint4* base = (uint4*)&ypack[(size_t)tile * 512];
            base[pos]      = blo;
            base[32 + pos] = bhi;
        }
        __syncthreads();

        // j-loop: 1 tile-pair read feeds 6 MFMAs (3 strips x 2 tiles)
        const unsigned short* lp = ypack + (size_t)lane * 8;
        #pragma unroll 2
        for (int j = 0; j < ntc; j += 2) {
            const short8 c0 = *reinterpret_cast<const short8*>(
                lp + (size_t)j * 512);
            const short8 c1 = (j + 1 < ntc)
                ? *reinterpret_cast<const short8*>(lp + (size_t)(j + 1) * 512)
                : c0;                     // odd tail: min(x,x)=x
            STRIP(rm0, a0, c0, c1);
            STRIP(rm1, a1, c0, c1);
            STRIP(rm2, a2, c0, c1);
        }
    }

    // epilogue: per-row min over 32 cols, store raw minima
    // D layout: col=lane&31, row=(r&3)+8*(r>>2)+4*(lane>>5)
    const size_t outb = (((size_t)dir * B + b) * YS + js) * (size_t)NpadMax;
    #pragma unroll
    for (int r = 0; r < 16; ++r) {
        const float v0 = allmin32(rm0[r]);
        const float v1 = allmin32(rm1[r]);
        const float v2 = allmin32(rm2[r]);
        if (lc == 0) {
            const int rr = (r & 3) + 8 * (r >> 2) + 4 * h;
            const int r0 = row0 + rr;
            if (r0 < Nx)      rowpart[outb + r0]      = v0;
            if (r0 + 32 < Nx) rowpart[outb + r0 + 32] = v1;
            if (r0 + 64 < Nx) rowpart[outb + r0 + 64] = v2;
        }
    }
}

__global__ __launch_bounds__(256) void combine_kernel(
    const float* __restrict__ rowpart, int B, int N, int M,
    int NpadMax, float invBN, float invBM, float* __restrict__ partial)
{
    const int tid = threadIdx.x;
    const int tot = 2 * B * NpadMax;
    float acc = 0.f;
    for (int idx = blockIdx.x * 256 + tid; idx < tot; idx += gridDim.x * 256) {
        const int row = idx % NpadMax;
        const int rem = idx / NpadMax;
        const int b   = rem % B;
        const int dir = rem / B;
        const int Nx  = (dir == 0) ? N : M;
        if (row >= Nx) continue;
        float m = __builtin_inff();
        #pragma unroll
        for (int js = 0; js < YS; ++js)
            m = fminf(m, rowpart[(((size_t)dir * B + b) * YS + js)
                                 * (size_t)NpadMax + row]);
        acc += fmaxf(m, 0.f) * ((dir == 0) ? invBN : invBM);
    }
    __shared__ float sb[256];
    sb[tid] = acc; __syncthreads();
    for (int off2 = 128; off2 > 0; off2 >>= 1) {
        if (tid < off2) sb[tid] += sb[tid + off2];
        __syncthreads();
    }
    if (tid == 0) partial[blockIdx.x] = sb[0];
}

__global__ void finalize_kernel(const float* __restrict__ partial, int np,
                                const float* __restrict__ fbpp, int Bf,
                                const void* __restrict__ lamp,
                                float* __restrict__ out)
{
    __shared__ float sb[256];
    const int tid = threadIdx.x;
    float acc = 0.f;
    for (int i = tid; i < np; i += 256) acc += partial[i];
    sb[tid] = acc;
    __syncthreads();
    for (int off = 128; off > 0; off >>= 1) {
        if (tid < off) sb[tid] += sb[tid + off];
        __syncthreads();
    }
    if (tid == 0) {
        const int li = *(const int*)lamp;
        const float lam = (li >= -1000000 && li <= 1000000)
                            ? (float)li : *(const float*)lamp;
        float fm = 0.f;
        for (int i = 0; i < Bf; ++i) fm += fbpp[i];
        fm /= (float)Bf;
        out[0] = sb[0] + lam * fm;
    }
}

extern "C" void kernel_launch(void* const* d_in, const int* in_sizes, int n_in,
                              void* d_out, int out_size, void* d_ws, size_t ws_size,
                              hipStream_t stream) {
    const float* pred = (const float*)d_in[0];
    const float* targ = (const float*)d_in[1];
    const float* fbpp = (const float*)d_in[2];
    const void*  lamp = d_in[3];

    const int B = in_sizes[2];
    const int N = in_sizes[0] / (3 * B);
    const int M = in_sizes[1] / (3 * B);
    const int NpadP = roundup_h(N, RPB);
    const int NpadT = roundup_h(M, RPB);
    const int NpadMax = (NpadP > NpadT) ? NpadP : NpadT;

    // ---- workspace: rowpart + partial ----
    float* rowpart = (float*)d_ws;
    float* partial = rowpart + (size_t)2 * B * YS * NpadMax;
    (void)ws_size;

    // ---- 1) fused pack+sweep (both directions) ----
    const int SP = NpadMax / RPB;
    const int blocks = 2 * B * YS * SP;
    fused_sweep<<<blocks, 256, 0, stream>>>(
        pred, targ, B, N, M, NpadP, NpadT, NpadMax, rowpart);

    // ---- 2) combine splits + clamp + weighted sum ----
    combine_kernel<<<256, 256, 0, stream>>>(
        rowpart, B, N, M, NpadMax,
        1.f / ((float)B * (float)N), 1.f / ((float)B * (float)M), partial);

    // ---- 3) finalize ----
    finalize_kernel<<<1, 256, 0, stream>>>(partial, 256, fbpp, B, lamp,
                                           (float*)d_out);
}

// Round 22
// 39.203 us; speedup vs baseline: 1.0563x; 1.0563x over previous
//
#include <hip/hip_runtime.h>
#include <math.h>

// Chamfer loss via MFMA (math verified r12-r21, absmax 0).
// Round-22 = r17 (best measured, 38.40us) + ONE variable: XCD-aware
// blockIdx swizzle in mfma_sweep. r15/r17 profile: sweep FETCH_SIZE 9.3MB
// at 103GB/s (latency-bound cold phase, F~15us) vs a 2.2MB pack -> ~4x
// over-fetch because consecutive blocks (same y-chunk, sp inner-most)
// round-robin across 8 non-coherent XCD L2s. Swizzle logical=(hw&7)*
// (nwg/8)+hw/8 (bijective, nwg=1024%8==0) puts all sp-blocks of a chunk
// (and all js-blocks of an A-chunk) on ONE XCD -> each line fetched once.

typedef __attribute__((ext_vector_type(8)))  short  short8;
typedef __attribute__((ext_vector_type(16))) float  f32x16;

#define YS      4     // j-range splits per (dir,b)
#define RPB     256   // rows per block = 4 waves * 64 (2 strips/wave)

#define MFMA2(da, db, A, B0, B1) \
    asm("v_mfma_f32_32x32x16_bf16 %0, %2, %3, 0\n\t" \
        "v_mfma_f32_32x32x16_bf16 %1, %2, %4, 0\n\t" \
        "s_nop 7\n\t" \
        "s_nop 7" \
        : "=&v"(da), "=&v"(db) \
        : "v"(A), "v"(B0), "v"(B1))

static __device__ __forceinline__ float min3f(float a, float b, float c) {
    float d;
    asm("v_min3_f32 %0, %1, %2, %3" : "=v"(d) : "v"(a), "v"(b), "v"(c));
    return d;
}

static inline int roundup_h(int v, int a) { return (v + a - 1) / a * a; }

static __device__ __forceinline__ unsigned short f2bf(float f) {
    union { float f; unsigned int u; } v; v.f = f;
    unsigned int r = v.u + 0x7FFFu + ((v.u >> 16) & 1u);  // RNE
    return (unsigned short)(r >> 16);
}
static __device__ __forceinline__ float bf2f(unsigned short s) {
    union { unsigned int u; float f; } v; v.u = ((unsigned int)s) << 16;
    return v.f;
}
static __device__ __forceinline__ unsigned int pk2(unsigned short lo,
                                                   unsigned short hi) {
    return (unsigned int)lo | ((unsigned int)hi << 16);
}

// all-reduce min over each 32-lane group: 4 DPP levels (VALU) + 1 swizzle
static __device__ __forceinline__ float allmin32(float v) {
    union { float f; int i; } u, t;
    u.f = v;
    t.i = __builtin_amdgcn_update_dpp(u.i, u.i, 0xB1, 0xF, 0xF, false);  // xor1
    u.f = fminf(u.f, t.f);
    t.i = __builtin_amdgcn_update_dpp(u.i, u.i, 0x4E, 0xF, 0xF, false);  // xor2
    u.f = fminf(u.f, t.f);
    t.i = __builtin_amdgcn_update_dpp(u.i, u.i, 0x124, 0xF, 0xF, false); // ror4
    u.f = fminf(u.f, t.f);
    t.i = __builtin_amdgcn_update_dpp(u.i, u.i, 0x128, 0xF, 0xF, false); // ror8
    u.f = fminf(u.f, t.f);
    t.i = __builtin_amdgcn_ds_swizzle(u.i, 0x401F);                      // xor16
    u.f = fminf(u.f, t.f);
    return u.f;
}

// A layout: per point i: 16 bf16 (two 16B halves, khalf h at +8 shorts).
// B layout: per (b): [tile][khalf][point] 16B units (tile=i>>5, p=i&31)
//  -> lane l's direct global read at tile*1024B + l*16B yields
//     point=l&31, khalf=l>>5, exactly the MFMA B-fragment.
__global__ __launch_bounds__(256) void pack_kernel(
    const float* __restrict__ pred, const float* __restrict__ targ,
    int B, int N, int M, int NpadP, int NpadT,
    unsigned short* __restrict__ aP, unsigned short* __restrict__ bP,
    unsigned short* __restrict__ aT, unsigned short* __restrict__ bT)
{
    const int padmax = (NpadP > NpadT) ? NpadP : NpadT;
    const int gid = blockIdx.x * 256 + threadIdx.x;
    if (gid >= B * padmax) return;
    const int b = gid / padmax, i = gid - b * padmax;

    for (int cloud = 0; cloud < 2; ++cloud) {
        const int cnt  = cloud ? M : N;
        const int npad = cloud ? NpadT : NpadP;
        if (i >= npad) continue;
        // padding duplicates the last point: harmless for min reductions
        const float* src = (cloud ? targ : pred) +
                           ((size_t)b * cnt + min(i, cnt - 1)) * 3;
        unsigned short* A  = (cloud ? aT : aP) + ((size_t)b * npad + i) * 16;
        unsigned short* Bk = (cloud ? bT : bP) + (size_t)b * npad * 16;

        const float xs[3] = {src[0], src[1], src[2]};
        const float n2 = xs[0]*xs[0] + xs[1]*xs[1] + xs[2]*xs[2];
        unsigned short th[3], tl[3], yh[3], yl[3];
        #pragma unroll
        for (int c = 0; c < 3; ++c) {
            const float t = -2.0f * xs[c];
            th[c] = f2bf(t);     tl[c] = f2bf(t - bf2f(th[c]));
            yh[c] = f2bf(xs[c]); yl[c] = f2bf(xs[c] - bf2f(yh[c]));
        }
        const unsigned short n2h = f2bf(n2);
        const unsigned short n2l = f2bf(n2 - bf2f(n2h));
        const unsigned short ONE = 0x3F80;

        uint4 alo, ahi, blo, bhi;
        alo.x = pk2(th[0], th[1]); alo.y = pk2(th[2], tl[0]);
        alo.z = pk2(tl[1], tl[2]); alo.w = pk2(th[0], th[1]);
        ahi.x = pk2(th[2], tl[0]); ahi.y = pk2(tl[1], tl[2]);
        ahi.z = pk2(ONE,  ONE);    ahi.w = pk2(n2h,  n2l);
        blo.x = pk2(yh[0], yh[1]); blo.y = pk2(yh[2], yh[0]);
        blo.z = pk2(yh[1], yh[2]); blo.w = pk2(yl[0], yl[1]);
        bhi.x = pk2(yl[2], yl[0]); bhi.y = pk2(yl[1], yl[2]);
        bhi.z = pk2(n2h,  n2l);    bhi.w = pk2(ONE,  ONE);

        *(uint4*)(A)     = alo;  *(uint4*)(A + 8) = ahi;
        const size_t tb = (size_t)(i >> 5) * 64 + (i & 31);   // 16B units
        *(uint4*)(Bk + tb * 8)        = blo;                   // khalf 0
        *(uint4*)(Bk + (tb + 32) * 8) = bhi;                   // khalf 1
    }
}

// Block = (dir, b, js, row-block of 256) AFTER XCD swizzle. 4 waves; wave w
// owns 64 rows (2 MFMA strips). B-fragments read DIRECTLY from global
// (L2-resident, coalesced 1KB wave-loads), 1-deep prefetch. No LDS/barriers.
__global__ __launch_bounds__(256, 4) void mfma_sweep(
    const unsigned short* __restrict__ aP, const unsigned short* __restrict__ bP,
    const unsigned short* __restrict__ aT, const unsigned short* __restrict__ bT,
    int B, int N, int M, int NpadP, int NpadT, int NpadMax,
    float* __restrict__ rowpart)
{
    const int tid  = threadIdx.x;
    const int w    = tid >> 6;
    const int lane = tid & 63;
    const int lc   = lane & 31, h = lane >> 5;

    // XCD-aware swizzle: same-XCD hardware blocks (hw%8 equal) get
    // CONSECUTIVE logical ids -> each y-chunk/A-chunk lives in ONE L2.
    // Bijective since gridDim.x % 8 == 0.
    const int cpx = (int)gridDim.x >> 3;
    const int hw  = (int)blockIdx.x;
    int t = (hw & 7) * cpx + (hw >> 3);

    const int SP = NpadMax / RPB;
    const int sp  = t % SP;  t /= SP;
    const int js  = t % YS;  t /= YS;
    const int b   = t % B;   t /= B;
    const int dir = t;

    const unsigned short* Xp = (dir == 0) ? aP : aT;
    const unsigned short* Yp = (dir == 0) ? bT : bP;
    const int NpadX = (dir == 0) ? NpadP : NpadT;
    const int NpadY = (dir == 0) ? NpadT : NpadP;
    const int Nx    = (dir == 0) ? N : M;
    if (sp * RPB >= NpadX) return;          // block-uniform

    // NpadY is a multiple of 256 -> TM mult of 8 -> nt0 = TM/YS exact
    const int TM  = NpadY / 32;
    const int nt0 = TM / YS;
    const int t0  = js * nt0;

    // A-frags (loop-invariant): row = lane&31, k = (lane>>5)*8 + e
    const int row0 = sp * RPB + w * 64;
    const size_t abase = ((size_t)b * NpadX + row0 + lc) * 16 + (size_t)h * 8;
    const short8 a0 = *reinterpret_cast<const short8*>(Xp + abase);
    const short8 a1 = *reinterpret_cast<const short8*>(Xp + abase + 32 * 16);

    f32x16 rm0, rm1;
    #pragma unroll
    for (int r = 0; r < 16; ++r) {
        rm0[r] = __builtin_inff(); rm1[r] = __builtin_inff();
    }

    // B-frag stream: tile j at yp + j*512 shorts (tile stride = 1KB)
    const unsigned short* yp =
        Yp + (size_t)b * NpadY * 16 + (size_t)t0 * 512 + (size_t)lane * 8;
    short8 c0 = *reinterpret_cast<const short8*>(yp);
    short8 c1 = *reinterpret_cast<const short8*>(yp + 512);

    for (int j = 0; j < nt0; j += 2) {
        // prefetch next pair (last iter reads <=2 tiles past the chunk:
        // covered by the 8KB slack after each pack buffer)
        const short8 n0 = *reinterpret_cast<const short8*>(yp + 1024);
        const short8 n1 = *reinterpret_cast<const short8*>(yp + 1536);
        yp += 1024;
        __builtin_amdgcn_sched_barrier(0);   // keep prefetch issued early
        {   // strip 0 (transient 32-reg D, then fold)
            f32x16 da, db;
            MFMA2(da, db, a0, c0, c1);
            #pragma unroll
            for (int r = 0; r < 16; ++r)
                rm0[r] = min3f(da[r], db[r], rm0[r]);   // 1 instr each
        }
        {   // strip 1
            f32x16 da, db;
            MFMA2(da, db, a1, c0, c1);
            #pragma unroll
            for (int r = 0; r < 16; ++r)
                rm1[r] = min3f(da[r], db[r], rm1[r]);
        }
        c0 = n0; c1 = n1;
    }

    // per-row min over 32 cols (DPP+swizzle all-reduce), then store.
    // D layout: col=lane&31, row=(r&3)+8*(r>>2)+4*(lane>>5)
    const size_t outb = (((size_t)dir * B + b) * YS + js) * (size_t)NpadMax;
    #pragma unroll
    for (int r = 0; r < 16; ++r) {
        const float v0 = allmin32(rm0[r]);
        const float v1 = allmin32(rm1[r]);
        if (lc == 0) {
            const int rr = (r & 3) + 8 * (r >> 2) + 4 * h;
            const int ra = row0 + rr, rb = row0 + 32 + rr;
            if (ra < Nx) rowpart[outb + ra] = v0;
            if (rb < Nx) rowpart[outb + rb] = v1;
        }
    }
}

__global__ __launch_bounds__(256) void combine_kernel(
    const float* __restrict__ rowpart, int B, int N, int M,
    int NpadP, int NpadT, int NpadMax,
    float invBN, float invBM, float* __restrict__ partial)
{
    const int tid = threadIdx.x;
    const int tot = 2 * B * NpadMax;
    float acc = 0.f;
    for (int idx = blockIdx.x * 256 + tid; idx < tot; idx += gridDim.x * 256) {
        const int row = idx % NpadMax;
        const int rem = idx / NpadMax;
        const int b   = rem % B;
        const int dir = rem / B;
        const int Nx  = (dir == 0) ? N : M;
        if (row >= Nx) continue;
        float m = __builtin_inff();
        #pragma unroll
        for (int js = 0; js < YS; ++js)
            m = fminf(m, rowpart[(((size_t)dir * B + b) * YS + js)
                                 * (size_t)NpadMax + row]);
        acc += fmaxf(m, 0.f) * ((dir == 0) ? invBN : invBM);
    }
    __shared__ float sb[256];
    sb[tid] = acc; __syncthreads();
    for (int off2 = 128; off2 > 0; off2 >>= 1) {
        if (tid < off2) sb[tid] += sb[tid + off2];
        __syncthreads();
    }
    if (tid == 0) partial[blockIdx.x] = sb[0];
}

__global__ void finalize_kernel(const float* __restrict__ partial, int np,
                                const float* __restrict__ fbpp, int Bf,
                                const void* __restrict__ lamp,
                                float* __restrict__ out)
{
    __shared__ float sb[256];
    const int tid = threadIdx.x;
    float acc = 0.f;
    for (int i = tid; i < np; i += 256) acc += partial[i];
    sb[tid] = acc;
    __syncthreads();
    for (int off = 128; off > 0; off >>= 1) {
        if (tid < off) sb[tid] += sb[tid + off];
        __syncthreads();
    }
    if (tid == 0) {
        const int li = *(const int*)lamp;
        const float lam = (li >= -1000000 && li <= 1000000)
                            ? (float)li : *(const float*)lamp;
        float fm = 0.f;
        for (int i = 0; i < Bf; ++i) fm += fbpp[i];
        fm /= (float)Bf;
        out[0] = sb[0] + lam * fm;
    }
}

extern "C" void kernel_launch(void* const* d_in, const int* in_sizes, int n_in,
                              void* d_out, int out_size, void* d_ws, size_t ws_size,
                              hipStream_t stream) {
    const float* pred = (const float*)d_in[0];
    const float* targ = (const float*)d_in[1];
    const float* fbpp = (const float*)d_in[2];
    const void*  lamp = d_in[3];

    const int B = in_sizes[2];
    const int N = in_sizes[0] / (3 * B);
    const int M = in_sizes[1] / (3 * B);
    const int NpadP = roundup_h(N, RPB);
    const int NpadT = roundup_h(M, RPB);
    const int NpadMax = (NpadP > NpadT) ? NpadP : NpadT;

    // ---- workspace layout (+8KB slack after each pack for prefetch OOB) ----
    size_t o = 0;
    auto take = [&](size_t bytes) {
        size_t r = o; o += (bytes + 255) & ~(size_t)255; return r;
    };
    unsigned short* aP = (unsigned short*)((char*)d_ws +
                         take((size_t)B * NpadP * 32 + 8192));
    unsigned short* bP = (unsigned short*)((char*)d_ws +
                         take((size_t)B * NpadP * 32 + 8192));
    unsigned short* aT = (unsigned short*)((char*)d_ws +
                         take((size_t)B * NpadT * 32 + 8192));
    unsigned short* bT = (unsigned short*)((char*)d_ws +
                         take((size_t)B * NpadT * 32 + 8192));
    float* rowpart = (float*)((char*)d_ws +
                     take((size_t)2 * B * YS * NpadMax * sizeof(float)));
    float* partial = (float*)((char*)d_ws + take(256 * sizeof(float)));
    (void)ws_size;

    // ---- 1) pack both clouds into A/B MFMA K-patterns ----
    pack_kernel<<<(B * NpadMax + 255) / 256, 256, 0, stream>>>(
        pred, targ, B, N, M, NpadP, NpadT, aP, bP, aT, bT);

    // ---- 2) MFMA pair sweep (both directions), XCD-swizzled ----
    const int SP = NpadMax / RPB;
    const int blocks = 2 * B * YS * SP;   // 1024 for 8192/4: %8==0
    mfma_sweep<<<blocks, 256, 0, stream>>>(
        aP, bP, aT, bT, B, N, M, NpadP, NpadT, NpadMax, rowpart);

    // ---- 3) combine splits + clamp + weighted sum ----
    combine_kernel<<<256, 256, 0, stream>>>(
        rowpart, B, N, M, NpadP, NpadT, NpadMax,
        1.f / ((float)B * (float)N), 1.f / ((float)B * (float)M), partial);

    // ---- 4) finalize ----
    finalize_kernel<<<1, 256, 0, stream>>>(partial, 256, fbpp, B, lamp,
                                           (float*)d_out);
}